// Round 8
// baseline (1432.301 us; speedup 1.0000x reference)
//
#include <hip/hip_runtime.h>

// RNN_16492674416646: h_t = tanh(x_t W_ih^T + b_ih + b_hh + h_{t-1} W_hh^T),
// out_t = h_t W_out^T + b_out. T=2048, B=128, IN=2, H=200, OUT=1, fp32.
//
// One block per batch element (128 blocks, 512 threads = 8 waves).
// Wave s owns k-slice [25s,25s+25); lane g<50 owns rows 4g..4g+3.
//
// R8 root cause of R2-R7's VGPR=40..68: __launch_bounds__(512,2) is only a
// MIN waves/EU; the backend still register-squeezes to reach 8 waves/EU
// (2 blocks/CU) -- useless here (grid=128 on 256 CUs, every block gets its
// own CU) -- parking weights in AGPRs/memory and paying per-step copies.
// amdgpu_waves_per_eu(2,2) pins min=max=2: budget 256 VGPRs, no occupancy
// incentive, weights stay hoisted SSA values in VGPRs. No asm pins (R5/R7's
// tied operands generated the AGPR<->VGPR copy churn).
//
// Weights held as 50 named float2 (row-pairs); __builtin_elementwise_fma on
// ext_vector float2 -> v_pk_fma_f32 (full-rate packed fp32): 50 instrs for
// 100 MACs. h broadcast: 1 ds_read_b32/wave + 25 v_readlane -> SGPR.
// Head: 8-deep LDS ring, drained every 8 steps by wave s (off critical path).

static constexpr int T = 2048;
static constexpr int B = 128;
static constexpr int H = 200;
static constexpr int KS = 25;     // k-slice width per wave
static constexpr int S  = 8;      // waves = slices
static constexpr int NTHR = 512;

typedef float v2f __attribute__((ext_vector_type(2)));

#define WLIST(X) X(0) X(1) X(2) X(3) X(4) X(5) X(6) X(7) X(8) X(9) \
    X(10) X(11) X(12) X(13) X(14) X(15) X(16) X(17) X(18) X(19) \
    X(20) X(21) X(22) X(23) X(24)

__global__ __attribute__((amdgpu_flat_work_group_size(NTHR, NTHR),
                          amdgpu_waves_per_eu(2, 2)))
void rnn_fused(const float* __restrict__ x,     // [T,B,2]
               const float* __restrict__ W_ih,  // [H,2]
               const float* __restrict__ W_hh,  // [H,H]
               const float* __restrict__ b_ih,  // [H]
               const float* __restrict__ b_hh,  // [H]
               const float* __restrict__ W_out, // [1,H]
               const float* __restrict__ b_out, // [1]
               float* __restrict__ out)         // [T,B]
{
    const int b    = blockIdx.x;
    const int tid  = threadIdx.x;
    const int s    = tid >> 6;          // wave id = k-slice id
    const int lane = tid & 63;
    const bool rowact = (lane < 50);
    const int g    = rowact ? lane : 49;   // clamp: harmless dup work
    const int j0   = 4 * g;
    const int k0   = KS * s;

    __shared__ __align__(16) float ring[8][H];   // h history, slot = t&7
    __shared__ __align__(16) float part[S][H];   // per-slice partials
    __shared__ float xs[2 * T];                  // x column (16 KB)

    // --- one-time: 100 weights as 50 NAMED float2 SSA values (row pairs) ---
    const float* r0 = W_hh + (j0 + 0) * H + k0;
    const float* r1 = W_hh + (j0 + 1) * H + k0;
    const float* r2 = W_hh + (j0 + 2) * H + k0;
    const float* r3 = W_hh + (j0 + 3) * H + k0;
#define DECLW(i) v2f W01_##i = {r0[i], r1[i]}; v2f W23_##i = {r2[i], r3[i]};
    WLIST(DECLW)
#undef DECLW

    // --- one-time: stage x[:, b, :] into LDS ---
    for (int idx = tid; idx < T; idx += NTHR) {
        const float2 v = *(const float2*)(x + (size_t)idx * (B * 2) + 2 * b);
        xs[2 * idx + 0] = v.x;
        xs[2 * idx + 1] = v.y;
    }

    // --- one-time: phase-2 constants; thread (s, lane<25) owns jp=25s+lane
    const int jp = 25 * s + ((lane < 25) ? lane : 24);
    const float wih0 = W_ih[jp * 2 + 0];
    const float wih1 = W_ih[jp * 2 + 1];
    const float bias = b_ih[jp] + b_hh[jp];

    // --- one-time: head constants (used every 8th step) ---
    const float wo0 = W_out[lane];
    const float wo1 = W_out[64 + lane];
    const float wo2 = W_out[128 + lane];
    const float wo3 = (lane < H - 192) ? W_out[192 + lane] : 0.f;
    const float bo  = b_out[0];

    if (tid < H) ring[7][tid] = 0.f;    // h_0 = 0 (step 0 reads slot 7)
    __syncthreads();

    float* op = out + b;

    for (int t = 0; t < T; ++t) {
        const float x0 = xs[2 * t + 0];
        const float x1 = xs[2 * t + 1];

        // --- phase 1: h slice (1 ds_read_b32/wave) -> SGPR -> pk_fma ---
        const int hidx = (lane < KS) ? lane : 0;
        const float hval = ring[(t + 7) & 7][k0 + hidx];

        v2f acc01 = {0.f, 0.f};
        v2f acc23 = {0.f, 0.f};
#define FMASTEP(i) { \
        const float hs_ = __int_as_float( \
            __builtin_amdgcn_readlane(__float_as_int(hval), i)); \
        const v2f hv_ = {hs_, hs_}; \
        acc01 = __builtin_elementwise_fma(W01_##i, hv_, acc01); \
        acc23 = __builtin_elementwise_fma(W23_##i, hv_, acc23); }
        WLIST(FMASTEP)
#undef FMASTEP

        if (rowact) {
            float4 v; v.x = acc01.x; v.y = acc01.y; v.z = acc23.x; v.w = acc23.y;
            *(float4*)&part[s][j0] = v;             // conflict-free b128
        }
        __syncthreads();

        // --- phase 2: 8 waves x 25 lanes, j = 25s+lane ---
        if (lane < 25) {
            const float p01 = part[0][jp] + part[1][jp];
            const float p23 = part[2][jp] + part[3][jp];
            const float p45 = part[4][jp] + part[5][jp];
            const float p67 = part[6][jp] + part[7][jp];
            const float sum = (p01 + p23) + (p45 + p67);
            const float pre = sum + fmaf(x0, wih0, fmaf(x1, wih1, bias));
            // tanh(x) = 1 - 2/(e^{2x}+1); saturates correctly at +-inf
            const float e = __expf(2.f * pre);
            ring[t & 7][jp] = 1.f - 2.f / (e + 1.f);
        }
        __syncthreads();

        // --- head, every 8 steps: wave s -> out[t-7+s] = ring[s].W_out ---
        // Each wave finishes its head before passing the next barrier1;
        // slot s is only rewritten after that barrier (phase 2).
        if ((t & 7) == 7) {
            const int l3 = (lane < H - 192) ? lane : 0;
            float v = ring[s][lane] * wo0 + ring[s][64 + lane] * wo1
                    + ring[s][128 + lane] * wo2 + ring[s][192 + l3] * wo3;
#pragma unroll
            for (int off = 32; off > 0; off >>= 1)
                v += __shfl_down(v, off, 64);
            if (lane == 0) op[(size_t)(t - 7 + s) * B] = v + bo;
        }
    }
}

extern "C" void kernel_launch(void* const* d_in, const int* in_sizes, int n_in,
                              void* d_out, int out_size, void* d_ws, size_t ws_size,
                              hipStream_t stream) {
    const float* x     = (const float*)d_in[0];
    const float* W_ih  = (const float*)d_in[1];
    const float* W_hh  = (const float*)d_in[2];
    const float* b_ih  = (const float*)d_in[3];
    const float* b_hh  = (const float*)d_in[4];
    const float* W_out = (const float*)d_in[5];
    const float* b_out = (const float*)d_in[6];
    float* out = (float*)d_out;

    rnn_fused<<<B, NTHR, 0, stream>>>(x, W_ih, W_hh, b_ih, b_hh, W_out, b_out, out);
}